// Round 7
// baseline (990.837 us; speedup 1.0000x reference)
//
#include <hip/hip_runtime.h>
#include <hip/hip_bf16.h>
#include <math.h>

typedef __attribute__((ext_vector_type(8))) short bf16x8;
typedef __attribute__((ext_vector_type(4))) float f32x4;

__device__ inline ushort f2bf(float f) {
    __hip_bfloat16 h = __float2bfloat16(f);
    return *reinterpret_cast<ushort*>(&h);
}
__device__ inline float bf2f(ushort u) {
    return __uint_as_float(((unsigned int)u) << 16);
}

// ---------------- K0a: CPB MLP table: (343,3) -> relu(512) -> (343,6) ----------------
__global__ __launch_bounds__(256) void k_cpb_table(
        const float* __restrict__ rtab, const float* __restrict__ w1,
        const float* __restrict__ b1, const float* __restrict__ w2,
        float* __restrict__ table_out) {
    int idx = blockIdx.x * 256 + threadIdx.x;
    if (idx >= 343 * 6) return;
    int r = idx / 6, head = idx - r * 6;
    float t0 = rtab[r*3+0], t1 = rtab[r*3+1], t2 = rtab[r*3+2];
    float s = 0.f;
    for (int j = 0; j < 512; ++j) {
        float a = t0*w1[j*3+0] + t1*w1[j*3+1] + t2*w1[j*3+2] + b1[j];
        a = fmaxf(a, 0.f);
        s += a * w2[head*512 + j];
    }
    table_out[idx] = s;   // layout [r][head]
}

// ---------------- K0b: gather + 16*sigmoid -> bias16[6][64][64] ----------------
__global__ __launch_bounds__(256) void k_bias16(
        const float* __restrict__ table_out, const int* __restrict__ ridx,
        float* __restrict__ bias16) {
    int idx = blockIdx.x * 256 + threadIdx.x;
    if (idx >= 6 * 64 * 64) return;
    int head = idx >> 12;
    int nm = idx & 4095;
    float v = table_out[ridx[nm] * 6 + head];
    bias16[idx] = 16.f / (1.f + expf(-v));
}

// ---------------- K0c: convert + fragment-swizzle weights fp32 -> bf16 ----------------
// Fragment-major layouts: one wave load = 64 lanes x 16B contiguous (1KB).
//  W1s: g=((c*6+ks)*4+j)*64+l      <- f1w[(c*64+j*16+fr)*192 + ks*32+fg*8]
//  W2s: g=((c*2+ks2)*12+j)*64+l    <- f2w[(j*16+fr)*768 + c*64+ks2*32+fg*8]
//  Wps: g=(ks*12+j)*64+l           <- pw [(j*16+fr)*192 + ks*32+fg*8]
//  Wqs: g=((g2*18+ct)*6+ks)*64+l   <- qkvw[(seg*192+g2*96+u*16+fr)*192 + ks*32+fg*8], ct=seg*6+u
__global__ __launch_bounds__(256) void k_wcvt(
        const float* __restrict__ qkvw, const float* __restrict__ f1w,
        const float* __restrict__ f2w, const float* __restrict__ pw,
        ushort* __restrict__ Wqs, ushort* __restrict__ W1s,
        ushort* __restrict__ W2s, ushort* __restrict__ Wps) {
    const int i = blockIdx.x * 256 + threadIdx.x;   // 216*256 = 55296
    const int l = i & 63, fr = l & 15, fg = l >> 4;
    const float* src = nullptr;
    ushort* dst = nullptr;
    if (i < 18432) {                       // W1s
        int r = i >> 6;
        int j = r & 3, r2 = r >> 2;
        int ks = r2 % 6, c = r2 / 6;
        src = f1w + (size_t)(c*64 + j*16 + fr)*192 + ks*32 + fg*8;
        dst = W1s + (size_t)i*8;
    } else if (i < 36864) {                // W2s
        int g2 = i - 18432;
        int r = g2 >> 6;
        int j = r % 12, r2 = r / 12;
        int ks2 = r2 & 1, c = r2 >> 1;
        src = f2w + (size_t)(j*16 + fr)*768 + c*64 + ks2*32 + fg*8;
        dst = W2s + (size_t)g2*8;
    } else if (i < 41472) {                // Wps
        int g2 = i - 36864;
        int r = g2 >> 6;                   // ks*12 + j
        int j = r % 12, ks = r / 12;
        src = pw + (size_t)(j*16 + fr)*192 + ks*32 + fg*8;
        dst = Wps + (size_t)g2*8;
    } else if (i < 55296) {                // Wqs
        int g2 = i - 41472;
        int r = g2 >> 6;                   // (grp*18+ct)*6+ks
        int ks = r % 6, r2 = r / 6;
        int ct = r2 % 18, grp = r2 / 18;
        int seg = ct / 6, u = ct % 6;
        src = qkvw + (size_t)(seg*192 + grp*96 + u*16 + fr)*192 + ks*32 + fg*8;
        dst = Wqs + (size_t)g2*8;
    } else return;
    #pragma unroll
    for (int e = 0; e < 8; ++e) dst[e] = f2bf(src[e]);
}

// ---------------- K1: LN1 + roll(-2) + window partition -> buf1 bf16 [win][n][c] ----------------
__global__ __launch_bounds__(256) void k_ln1(
        const float* __restrict__ x, const float* __restrict__ nw,
        const float* __restrict__ nb, ushort* __restrict__ buf1) {
    const int wb = blockIdx.x;            // 0..1727
    const int b = wb / 216, win = wb - b * 216;
    const int wdi = win / 36, whi = (win / 6) % 6, wwi = win % 6;
    const int t = threadIdx.x;
    const int n = t >> 2, sub = t & 3;    // 4 lanes per token, 48 ch each
    const int id = n >> 4, ih = (n >> 2) & 3, iw = n & 3;
    const int dsrc = (wdi*4 + id + 2) % 24;
    const int hsrc = (whi*4 + ih + 2) % 24;
    const int wsrc = (wwi*4 + iw + 2) % 24;
    const float* xr = x + (size_t)(((b*24 + dsrc)*24 + hsrc)*24 + wsrc) * 192 + sub*48;
    float4 q[12];
    float sum = 0.f, ssum = 0.f;
    #pragma unroll
    for (int j = 0; j < 12; ++j) {
        q[j] = reinterpret_cast<const float4*>(xr)[j];
        sum  += q[j].x + q[j].y + q[j].z + q[j].w;
        ssum += q[j].x*q[j].x + q[j].y*q[j].y + q[j].z*q[j].z + q[j].w*q[j].w;
    }
    sum  += __shfl_xor(sum, 1);  sum  += __shfl_xor(sum, 2);
    ssum += __shfl_xor(ssum, 1); ssum += __shfl_xor(ssum, 2);
    float mu = sum * (1.f/192.f);
    float inv = rsqrtf(ssum * (1.f/192.f) - mu*mu + 1e-5f);
    ushort* op = buf1 + ((size_t)wb*64 + n)*192 + sub*48;
    #pragma unroll
    for (int j = 0; j < 12; ++j) {
        int c = sub*48 + j*4;
        ushort4 o;
        o.x = f2bf((q[j].x - mu)*inv*nw[c+0] + nb[c+0]);
        o.y = f2bf((q[j].y - mu)*inv*nw[c+1] + nb[c+1]);
        o.z = f2bf((q[j].z - mu)*inv*nw[c+2] + nb[c+2]);
        o.w = f2bf((q[j].w - mu)*inv*nw[c+3] + nb[c+3]);
        *reinterpret_cast<ushort4*>(op + j*4) = o;
    }
}

// ---------------- K2: fused QKV (MFMA) + cosine attn + bias + mask + softmax + PV ----------------
__global__ __launch_bounds__(256) void k_attn3(
        const ushort* __restrict__ buf1, const ushort* __restrict__ Wqs,
        const float* __restrict__ ls, const float* __restrict__ bias16,
        const float* __restrict__ amask, ushort* __restrict__ buf2) {
    __shared__ ushort QK[2][3][64][40];   // [q/k][head][n][d pad40]  30720 B
    __shared__ ushort Vt[3][32][72];      // [head][d][n pad72]       13824 B
    __shared__ ushort Pl[4][16][72];      // per-wave P rows          9216 B
    const int wb = blockIdx.x;
    const int win = wb % 216;
    const int t = threadIdx.x;
    const int wid = t >> 6, lane = t & 63;
    const int fr = lane & 15, fg = lane >> 4;
    const int trow = wid * 16;
    const ushort* Abase = buf1 + (size_t)wb * 12288 + (size_t)(trow + fr) * 192 + fg * 8;

    for (int g = 0; g < 2; ++g) {
        if (g) __syncthreads();
        // ---- QKV GEMM for heads g*3..g*3+2: 18 col-tiles (Q:6, K:6, V:6) ----
        f32x4 acc[18] = {};
        #pragma unroll
        for (int ks = 0; ks < 6; ++ks) {
            bf16x8 a = *(const bf16x8*)(Abase + ks*32);
            #pragma unroll
            for (int ct = 0; ct < 18; ++ct) {
                bf16x8 b = *(const bf16x8*)(Wqs + ((size_t)((g*18 + ct)*6 + ks)*64 + lane)*8);
                acc[ct] = __builtin_amdgcn_mfma_f32_16x16x32_bf16(a, b, acc[ct], 0, 0, 0);
            }
        }
        // ---- epilogue -> LDS (Q/K [n][d], V transposed [d][n]) ----
        #pragma unroll
        for (int ct = 0; ct < 18; ++ct) {
            const int seg = ct / 6, u = ct % 6;
            const int hl = u >> 1, dp = u & 1;
            if (seg < 2) {
                #pragma unroll
                for (int e = 0; e < 4; ++e)
                    QK[seg][hl][trow + fg*4 + e][dp*16 + fr] = f2bf(acc[ct][e]);
            } else {
                ushort4 v4;
                v4.x = f2bf(acc[ct][0]); v4.y = f2bf(acc[ct][1]);
                v4.z = f2bf(acc[ct][2]); v4.w = f2bf(acc[ct][3]);
                *reinterpret_cast<ushort4*>(&Vt[hl][dp*16 + fr][trow + fg*4]) = v4;
            }
        }
        __syncthreads();
        // ---- normalize Q (fold logit scale) and K rows, fp32 ----
        {
            float scq[3];
            #pragma unroll
            for (int hl = 0; hl < 3; ++hl)
                scq[hl] = expf(fminf(ls[g*3 + hl], 4.6051701859880914f));
            for (int rr = t; rr < 384; rr += 256) {
                const int mat = rr / 192, rem = rr - mat*192;
                const int hl = rem >> 6, n = rem & 63;
                ushort* p = &QK[mat][hl][n][0];
                float vals[32];
                float ss = 0.f;
                #pragma unroll
                for (int j = 0; j < 8; ++j) {
                    ushort4 u4 = *reinterpret_cast<const ushort4*>(p + j*4);
                    float a0 = bf2f(u4.x), a1 = bf2f(u4.y), a2 = bf2f(u4.z), a3 = bf2f(u4.w);
                    vals[j*4+0]=a0; vals[j*4+1]=a1; vals[j*4+2]=a2; vals[j*4+3]=a3;
                    ss += a0*a0 + a1*a1 + a2*a2 + a3*a3;
                }
                float f = 1.f / fmaxf(sqrtf(ss), 1e-12f);
                if (mat == 0) f *= (hl == 0 ? scq[0] : (hl == 1 ? scq[1] : scq[2]));
                #pragma unroll
                for (int j = 0; j < 8; ++j) {
                    ushort4 o;
                    o.x = f2bf(vals[j*4+0]*f); o.y = f2bf(vals[j*4+1]*f);
                    o.z = f2bf(vals[j*4+2]*f); o.w = f2bf(vals[j*4+3]*f);
                    *reinterpret_cast<ushort4*>(p + j*4) = o;
                }
            }
        }
        __syncthreads();
        // ---- per-head attention; wave-private rows [trow, trow+16) ----
        #pragma unroll 1
        for (int hl = 0; hl < 3; ++hl) {
            const int h = g*3 + hl;
            bf16x8 qf = *(const bf16x8*)&QK[0][hl][trow + fr][fg*8];
            f32x4 accS[4] = {};
            #pragma unroll
            for (int j = 0; j < 4; ++j) {
                bf16x8 kf = *(const bf16x8*)&QK[1][hl][j*16 + fr][fg*8];
                accS[j] = __builtin_amdgcn_mfma_f32_16x16x32_bf16(qf, kf, accS[j], 0, 0, 0);
            }
            float s[4][4];
            const float* bi = bias16 + h*4096;
            const float* mk = amask + (size_t)win*4096;
            #pragma unroll
            for (int e = 0; e < 4; ++e) {
                const int r = trow + fg*4 + e;
                #pragma unroll
                for (int j = 0; j < 4; ++j) {
                    const int c = j*16 + fr;
                    s[j][e] = accS[j][e] + bi[r*64 + c] + mk[r*64 + c];
                }
            }
            #pragma unroll
            for (int e = 0; e < 4; ++e) {
                float m0 = fmaxf(fmaxf(s[0][e], s[1][e]), fmaxf(s[2][e], s[3][e]));
                m0 = fmaxf(m0, __shfl_xor(m0, 1));
                m0 = fmaxf(m0, __shfl_xor(m0, 2));
                m0 = fmaxf(m0, __shfl_xor(m0, 4));
                m0 = fmaxf(m0, __shfl_xor(m0, 8));
                float s0 = 0.f;
                #pragma unroll
                for (int j = 0; j < 4; ++j) { s[j][e] = expf(s[j][e] - m0); s0 += s[j][e]; }
                s0 += __shfl_xor(s0, 1);
                s0 += __shfl_xor(s0, 2);
                s0 += __shfl_xor(s0, 4);
                s0 += __shfl_xor(s0, 8);
                const float rs = 1.f / s0;
                #pragma unroll
                for (int j = 0; j < 4; ++j)
                    Pl[wid][fg*4 + e][j*16 + fr] = f2bf(s[j][e] * rs);
            }
            f32x4 accO[2] = {};
            #pragma unroll
            for (int kk = 0; kk < 2; ++kk) {
                bf16x8 pa = *(const bf16x8*)&Pl[wid][fr][kk*32 + fg*8];
                #pragma unroll
                for (int j = 0; j < 2; ++j) {
                    bf16x8 vb = *(const bf16x8*)&Vt[hl][j*16 + fr][kk*32 + fg*8];
                    accO[j] = __builtin_amdgcn_mfma_f32_16x16x32_bf16(pa, vb, accO[j], 0, 0, 0);
                }
            }
            #pragma unroll
            for (int j = 0; j < 2; ++j) {
                #pragma unroll
                for (int e = 0; e < 4; ++e) {
                    buf2[(size_t)wb*12288 + (size_t)(trow + fg*4 + e)*192 + h*32 + j*16 + fr]
                        = f2bf(accO[j][e]);
                }
            }
        }
    }
}

// ---------------- K3: proj (MFMA bf16) + window reverse + roll(+2) + residual ----------------
__global__ __launch_bounds__(256) void k_proj(
        const ushort* __restrict__ buf2, const float* __restrict__ x,
        const ushort* __restrict__ Wps, const float* __restrict__ pb,
        float* __restrict__ out) {
    __shared__ ushort As[64 * 200];
    __shared__ int rowbase[64];
    const int t = threadIdx.x;
    const size_t base = (size_t)blockIdx.x * 64;
    if (t < 64) {
        int dst = (int)base + t;
        int b = dst / 13824, r1 = dst - b * 13824;
        int d = r1 / 576, h2 = (r1 / 24) % 24, w2 = r1 % 24;
        int dd = (d + 22) % 24, hh = (h2 + 22) % 24, ww = (w2 + 22) % 24;
        int win = ((dd >> 2)*6 + (hh >> 2))*6 + (ww >> 2);
        int n = ((dd & 3) << 4) | ((hh & 3) << 2) | (ww & 3);
        rowbase[t] = ((b*216 + win)*64 + n) * 192;
    }
    __syncthreads();
    {
        const int r = t >> 2, q = t & 3;
        const ushort* src = buf2 + rowbase[r] + q*48;
        #pragma unroll
        for (int i = 0; i < 6; ++i)
            *(bf16x8*)(As + r*200 + q*48 + i*8) = *(const bf16x8*)(src + i*8);
    }
    __syncthreads();

    const int wid = t >> 6, lane = t & 63;
    const int fr = lane & 15, fg = lane >> 4;
    const int trow = wid * 16;
    f32x4 acc[12] = {};
    #pragma unroll
    for (int ks = 0; ks < 6; ++ks) {
        bf16x8 a = *(const bf16x8*)(As + (trow + fr)*200 + ks*32 + fg*8);
        #pragma unroll
        for (int j = 0; j < 12; ++j) {
            bf16x8 b = *(const bf16x8*)(Wps + ((size_t)(ks*12 + j)*64 + lane)*8);
            acc[j] = __builtin_amdgcn_mfma_f32_16x16x32_bf16(a, b, acc[j], 0, 0, 0);
        }
    }
    #pragma unroll
    for (int j = 0; j < 12; ++j) {
        int c = j*16 + fr;
        float bias = pb[c];
        #pragma unroll
        for (int e = 0; e < 4; ++e) {
            size_t idx = (base + trow + fg*4 + e)*192 + c;
            out[idx] = x[idx] + acc[j][e] + bias;
        }
    }
}

// ---------------- K4: fused LN2 + FC1 + GELU + FC2 + residual (barrier-free) ----------------
// 864 blocks x 128 tokens; 4 waves x 32 tokens, wave-private. LN2 via cross-lane
// shuffle directly into A-fragments (no LDS); only Hs (17.4KB) in LDS; weights
// in fragment-major layout -> every wave B-load is 1KB contiguous.
__global__ __launch_bounds__(256, 4) void k_mlp3(
        const ushort* __restrict__ W1s, const ushort* __restrict__ W2s,
        const float* __restrict__ n2w, const float* __restrict__ n2b,
        const float* __restrict__ f1b, const float* __restrict__ f2b,
        float* __restrict__ out) {
    __shared__ ushort Hs[4][32][68];
    const int t = threadIdx.x;
    const int wid = t >> 6, lane = t & 63;
    const int fr = lane & 15, fg = lane >> 4;
    const size_t tok0 = (size_t)blockIdx.x * 128 + wid * 32;  // wave-owned 32 tokens

    // ---- LN2 -> A fragments in registers (shuffle over fg lanes) ----
    bf16x8 a[2][6];
    #pragma unroll
    for (int tf = 0; tf < 2; ++tf) {
        const float* hp = out + (tok0 + tf*16 + fr) * 192 + fg*8;
        float4 q[12];
        float sum = 0.f, ssum = 0.f;
        #pragma unroll
        for (int ks = 0; ks < 6; ++ks) {
            q[ks*2]   = *reinterpret_cast<const float4*>(hp + ks*32);
            q[ks*2+1] = *reinterpret_cast<const float4*>(hp + ks*32 + 4);
        }
        #pragma unroll
        for (int j = 0; j < 12; ++j) {
            sum  += q[j].x + q[j].y + q[j].z + q[j].w;
            ssum += q[j].x*q[j].x + q[j].y*q[j].y + q[j].z*q[j].z + q[j].w*q[j].w;
        }
        sum  += __shfl_xor(sum, 16);  sum  += __shfl_xor(sum, 32);
        ssum += __shfl_xor(ssum, 16); ssum += __shfl_xor(ssum, 32);
        float mu = sum * (1.f/192.f);
        float inv = rsqrtf(ssum * (1.f/192.f) - mu*mu + 1e-5f);
        #pragma unroll
        for (int ks = 0; ks < 6; ++ks) {
            const int c = ks*32 + fg*8;
            float4 w0 = *reinterpret_cast<const float4*>(n2w + c);
            float4 w1 = *reinterpret_cast<const float4*>(n2w + c + 4);
            float4 b0 = *reinterpret_cast<const float4*>(n2b + c);
            float4 b1 = *reinterpret_cast<const float4*>(n2b + c + 4);
            a[tf][ks][0] = (short)f2bf((q[ks*2].x   - mu)*inv*w0.x + b0.x);
            a[tf][ks][1] = (short)f2bf((q[ks*2].y   - mu)*inv*w0.y + b0.y);
            a[tf][ks][2] = (short)f2bf((q[ks*2].z   - mu)*inv*w0.z + b0.z);
            a[tf][ks][3] = (short)f2bf((q[ks*2].w   - mu)*inv*w0.w + b0.w);
            a[tf][ks][4] = (short)f2bf((q[ks*2+1].x - mu)*inv*w1.x + b1.x);
            a[tf][ks][5] = (short)f2bf((q[ks*2+1].y - mu)*inv*w1.y + b1.y);
            a[tf][ks][6] = (short)f2bf((q[ks*2+1].z - mu)*inv*w1.z + b1.z);
            a[tf][ks][7] = (short)f2bf((q[ks*2+1].w - mu)*inv*w1.w + b1.w);
        }
    }

    f32x4 acc2[2][12] = {};

    for (int c = 0; c < 12; ++c) {
        // ---- FC1: 32 tok x 64 hidden ----
        f32x4 acc1[2][4] = {};
        #pragma unroll
        for (int ks = 0; ks < 6; ++ks) {
            bf16x8 b[4];
            #pragma unroll
            for (int j = 0; j < 4; ++j)
                b[j] = *(const bf16x8*)(W1s + ((size_t)((c*6 + ks)*4 + j)*64 + lane)*8);
            #pragma unroll
            for (int j = 0; j < 4; ++j) {
                acc1[0][j] = __builtin_amdgcn_mfma_f32_16x16x32_bf16(a[0][ks], b[j], acc1[0][j], 0, 0, 0);
                acc1[1][j] = __builtin_amdgcn_mfma_f32_16x16x32_bf16(a[1][ks], b[j], acc1[1][j], 0, 0, 0);
            }
        }
        // ---- bias + GELU -> Hs (wave-private) ----
        #pragma unroll
        for (int j = 0; j < 4; ++j) {
            float bias = f1b[c*64 + j*16 + fr];
            #pragma unroll
            for (int tf = 0; tf < 2; ++tf) {
                #pragma unroll
                for (int e = 0; e < 4; ++e) {
                    float h = acc1[tf][j][e] + bias;
                    h = 0.5f*h*(1.f + erff(h*0.70710678118654752f));
                    Hs[wid][tf*16 + fg*4 + e][j*16 + fr] = f2bf(h);
                }
            }
        }
        // ---- FC2 partial over this hidden chunk ----
        #pragma unroll
        for (int ks2 = 0; ks2 < 2; ++ks2) {
            bf16x8 ha0 = *(const bf16x8*)&Hs[wid][fr][ks2*32 + fg*8];
            bf16x8 ha1 = *(const bf16x8*)&Hs[wid][16 + fr][ks2*32 + fg*8];
            #pragma unroll
            for (int j = 0; j < 12; ++j) {
                bf16x8 b = *(const bf16x8*)(W2s + ((size_t)((c*2 + ks2)*12 + j)*64 + lane)*8);
                acc2[0][j] = __builtin_amdgcn_mfma_f32_16x16x32_bf16(ha0, b, acc2[0][j], 0, 0, 0);
                acc2[1][j] = __builtin_amdgcn_mfma_f32_16x16x32_bf16(ha1, b, acc2[1][j], 0, 0, 0);
            }
        }
    }

    // ---- epilogue: out += mlp + f2b ----
    #pragma unroll
    for (int j = 0; j < 12; ++j) {
        int cch = j*16 + fr;
        float bias = f2b[cch];
        #pragma unroll
        for (int tf = 0; tf < 2; ++tf) {
            #pragma unroll
            for (int e = 0; e < 4; ++e) {
                size_t idx = (tok0 + tf*16 + fg*4 + e)*192 + cch;
                out[idx] += acc2[tf][j][e] + bias;
            }
        }
    }
}

extern "C" void kernel_launch(void* const* d_in, const int* in_sizes, int n_in,
                              void* d_out, int out_size, void* d_ws, size_t ws_size,
                              hipStream_t stream) {
    const float* x     = (const float*)d_in[0];
    const float* n1w   = (const float*)d_in[1];
    const float* n1b   = (const float*)d_in[2];
    const float* qkvw  = (const float*)d_in[3];
    const float* ls    = (const float*)d_in[6];
    const float* cpw1  = (const float*)d_in[7];
    const float* cpb1  = (const float*)d_in[8];
    const float* cpw2  = (const float*)d_in[9];
    const float* pw    = (const float*)d_in[10];
    const float* pb    = (const float*)d_in[11];
    const float* n2w   = (const float*)d_in[12];
    const float* n2b   = (const float*)d_in[13];
    const float* f1w   = (const float*)d_in[14];
    const float* f1b   = (const float*)d_in[15];
    const float* f2w   = (const float*)d_in[16];
    const float* f2b   = (const float*)d_in[17];
    const float* rtab  = (const float*)d_in[18];
    const int*   ridx  = (const int*)d_in[19];
    const float* amask = (const float*)d_in[20];
    float* out = (float*)d_out;

    // ws layout (all bf16/ushort unless noted); total ~86 MB
    ushort* buf1 = (ushort*)d_ws;          // 21233664 (LN1'd x, [win][n][c])
    ushort* buf2 = buf1 + 21233664;        // 21233664 (attn out, [win][n][c])
    ushort* Wqs  = buf2 + 21233664;        // 110592 (fragment-major)
    ushort* W1s  = Wqs + 110592;           // 147456 (fragment-major)
    ushort* W2s  = W1s + 147456;           // 147456 (fragment-major)
    ushort* Wps  = W2s + 147456;           // 36864  (fragment-major)
    float*  tblo = (float*)(Wps + 36864);  // 2058 (+pad)
    float*  b16  = tblo + 2064;            // 24576

    k_cpb_table<<<dim3(9),    dim3(256), 0, stream>>>(rtab, cpw1, cpb1, cpw2, tblo);
    k_bias16   <<<dim3(96),   dim3(256), 0, stream>>>(tblo, ridx, b16);
    k_wcvt     <<<dim3(216),  dim3(256), 0, stream>>>(qkvw, f1w, f2w, pw, Wqs, W1s, W2s, Wps);
    k_ln1      <<<dim3(1728), dim3(256), 0, stream>>>(x, n1w, n1b, buf1);
    k_attn3    <<<dim3(1728), dim3(256), 0, stream>>>(buf1, Wqs, ls, b16, amask, buf2);
    k_proj     <<<dim3(1728), dim3(256), 0, stream>>>(buf2, x, Wps, pb, out);
    k_mlp3     <<<dim3(864),  dim3(256), 0, stream>>>(W1s, W2s, n2w, n2b, f1b, f2b, out);
}